// Round 7
// baseline (426.563 us; speedup 1.0000x reference)
//
#include <hip/hip_runtime.h>
#include <hip/hip_bf16.h>
#include <stdint.h>

// Problem constants (from reference setup_inputs)
#define M_DIM   32768        // B*S = 32*1024
#define IN_DIM  1152
#define OUT_DIM 1152
#define R_DIM   64
#define QMAXF   255.0f

#define MM_BLOCKS 2048                       // minmax-role blocks
#define WP_BLOCKS (OUT_DIM * IN_DIM / 256)   // 5184 weight-fold blocks
#define QBLOCKS   4096

typedef float  f32x4  __attribute__((ext_vector_type(4)));
typedef __bf16 bf16x8 __attribute__((ext_vector_type(8)));

// RNE float -> bf16 bits (finite inputs only)
static __device__ __forceinline__ unsigned short f2bf(float f) {
    unsigned int u = __float_as_uint(f);
    unsigned int r = (u + 0x7fffu + ((u >> 16) & 1u)) >> 16;
    return (unsigned short)r;
}

// ---------------- Pass 0: role-split prep kernel --------------------------------
// Blocks [0, MM_BLOCKS):       global min/max of x * (1/scales) -> partials
// Blocks [MM_BLOCKS, +WP_BLOCKS): Wc[o][i] = qw[o][i] + sum_r lw[o][r]*rw[r][i] (bf16)
//                                 + rs[c] = 1/scales[c] (for k_quantf)
__global__ __launch_bounds__(256) void k_prep(const float* __restrict__ x,
                                              const float* __restrict__ scales,
                                              const float* __restrict__ qw,
                                              const float* __restrict__ rw,
                                              const float* __restrict__ lw,
                                              unsigned short* __restrict__ wc,
                                              float* __restrict__ rs,
                                              float* __restrict__ partials) {
    __shared__ __align__(16) float srs[IN_DIM];   // minmax role: per-block recip table
    __shared__ float smn[4], smx[4];

    if (blockIdx.x < MM_BLOCKS) {
        // ---- minmax role ----
        for (int c = threadIdx.x; c < IN_DIM; c += 256)
            srs[c] = 1.0f / scales[c];
        __syncthreads();

        const int n4 = (M_DIM * IN_DIM) / 4;      // 9,437,184 float4s; 2048*256*18
        int tid = blockIdx.x * 256 + threadIdx.x;
        const int stride = MM_BLOCKS * 256;
        float mn = 3.4e38f, mx = -3.4e38f;
        for (int i4 = tid; i4 < n4; i4 += stride) {
            int i = i4 * 4;
            float4 xv = *(const float4*)(x + i);
            int c = i % IN_DIM;                   // IN_DIM % 4 == 0 -> 16B aligned
            float4 sv = *(const float4*)(&srs[c]);
            float a0 = xv.x * sv.x, a1 = xv.y * sv.y;
            float a2 = xv.z * sv.z, a3 = xv.w * sv.w;
            mn = fminf(mn, fminf(fminf(a0, a1), fminf(a2, a3)));
            mx = fmaxf(mx, fmaxf(fmaxf(a0, a1), fmaxf(a2, a3)));
        }
        #pragma unroll
        for (int off = 32; off > 0; off >>= 1) {
            mn = fminf(mn, __shfl_down(mn, off));
            mx = fmaxf(mx, __shfl_down(mx, off));
        }
        int lane = threadIdx.x & 63, wv = threadIdx.x >> 6;
        if (lane == 0) { smn[wv] = mn; smx[wv] = mx; }
        __syncthreads();
        if (threadIdx.x == 0) {
            float bmn = fminf(fminf(smn[0], smn[1]), fminf(smn[2], smn[3]));
            float bmx = fmaxf(fmaxf(smx[0], smx[1]), fmaxf(smx[2], smx[3]));
            partials[blockIdx.x * 2]     = bmn;
            partials[blockIdx.x * 2 + 1] = bmx;
        }
    } else {
        // ---- weight-fold role ----
        int idx = (blockIdx.x - MM_BLOCKS) * 256 + threadIdx.x;  // over OUT*IN, exact
        if (idx < IN_DIM) rs[idx] = 1.0f / scales[idx];
        int o = idx / IN_DIM;
        int i = idx - o * IN_DIM;
        float acc = qw[idx];
        #pragma unroll 8
        for (int r = 0; r < R_DIM; r++)
            acc += lw[o * R_DIM + r] * rw[r * IN_DIM + i];
        wc[idx] = f2bf(acc);
    }
}

// ---------------- Pass 1: fused finalize + quantize ------------------------------
// Every block reduces the 2048 partial pairs (16 KB, L2-hit) -> qs, zp, lo, hi, rqs
// (deterministic, identical in all blocks). Block 0 publishes qp[0]=qs for k_gemm.
// Then stream-quantize: q - zp = clamp(rint((x*rs)*rqs), -zp, 255-zp), exact bf16.
__global__ __launch_bounds__(256) void k_quantf(const float* __restrict__ x,
                                                const float* __restrict__ rs,
                                                const float* __restrict__ partials,
                                                float* __restrict__ qp,
                                                unsigned short* __restrict__ xq) {
    __shared__ float smn[4], smx[4];
    __shared__ float s_lo, s_hi, s_rqs;

    float mn = 3.4e38f, mx = -3.4e38f;
    for (int i = threadIdx.x; i < MM_BLOCKS; i += 256) {   // 8 iters
        mn = fminf(mn, partials[i * 2]);
        mx = fmaxf(mx, partials[i * 2 + 1]);
    }
    #pragma unroll
    for (int off = 32; off > 0; off >>= 1) {
        mn = fminf(mn, __shfl_down(mn, off));
        mx = fmaxf(mx, __shfl_down(mx, off));
    }
    int lane = threadIdx.x & 63, wv = threadIdx.x >> 6;
    if (lane == 0) { smn[wv] = mn; smx[wv] = mx; }
    __syncthreads();
    if (threadIdx.x == 0) {
        float bmn = fminf(fminf(smn[0], smn[1]), fminf(smn[2], smn[3]));
        float bmx = fmaxf(fmaxf(smx[0], smx[1]), fmaxf(smx[2], smx[3]));
        float qs = (bmx - bmn) / QMAXF;
        float zp = rintf(-bmn / qs);
        s_lo  = -zp;               // clamp lo for (q - zp)
        s_hi  = QMAXF - zp;        // clamp hi for (q - zp)
        s_rqs = 1.0f / qs;
        if (blockIdx.x == 0) qp[0] = qs;       // for gemm epilogue (stream-ordered)
    }
    __syncthreads();
    const float lo = s_lo, hi = s_hi, rqs = s_rqs;

    const int n4 = (M_DIM * IN_DIM) / 4;
    int tid = blockIdx.x * 256 + threadIdx.x;
    const int stride = QBLOCKS * 256;
    for (int i4 = tid; i4 < n4; i4 += stride) {
        int i = i4 * 4;
        float4 xv = *(const float4*)(x + i);
        int c = i % IN_DIM;
        float4 sv = *(const float4*)(rs + c);
        float a[4] = { (xv.x * sv.x) * rqs, (xv.y * sv.y) * rqs,
                       (xv.z * sv.z) * rqs, (xv.w * sv.w) * rqs };
        ushort4 o;
        unsigned short* op = (unsigned short*)&o;
        #pragma unroll
        for (int j = 0; j < 4; j++) {
            float q = rintf(a[j]);
            q = fminf(fmaxf(q, lo), hi);
            op[j] = f2bf(q);                  // integer in [-255,255]: exact in bf16
        }
        *(ushort4*)(xq + i) = o;
    }
}

// ---------------- Pass 2: GEMM  C = qs * (A @ Wc^T) + bias -----------------------
// A: [M][K] bf16 (q - zp), Wc: [N][K] bf16, C: [M][N] fp32
// Structure: single-buffer BK=32, dim3(256,9) grid (R0-proven), with:
//  * T2 XOR swizzle of the 16B col-block: cb' = cb ^ ((row>>1)&3). Applied on the
//    GLOBAL SOURCE (staging) + the READ index; LDS dest stays linear (rule 21:
//    global_load_lds writes base+lane*16 only). Kills the 8-way ds_read_b128
//    bank conflict (lanes previously strided 64 B -> 2 bank-quads).
//  * Prefetch-after-reads: sync(stage t landed) -> ds_read frags -> sync(reads
//    done) -> issue stage(t+1) -> MFMA(t). glds latency overlaps MFMA.
//  * Swapped-operand MFMA (acc = bf x af = C^T fragment): lane holds 4 consecutive
//    columns -> float4 C-stores (16 stores/thread instead of 64).
#define BM 128
#define BN 128
#define BK 32
#define NT (IN_DIM / BK)      // 36 K-tiles

__global__ __launch_bounds__(256) void k_gemm(const unsigned short* __restrict__ A,
                                              const unsigned short* __restrict__ Bw,
                                              const float* __restrict__ bias,
                                              const float* __restrict__ qp,
                                              float* __restrict__ C) {
    __shared__ __align__(16) unsigned short As[BM * BK];   // 8 KB
    __shared__ __align__(16) unsigned short Bs[BN * BK];   // 8 KB
    const int tid = threadIdx.x;
    const int bm = blockIdx.x, bn = blockIdx.y;
    const int K = IN_DIM, N = OUT_DIM;

    // Staging: 512 x 16B units per tile; thread t fills units t and t+256 (linear
    // LDS dest). Unit u = row(u>>2), stored col-block (u&3); the DATA placed there
    // is global col-block (u&3) ^ ((row>>1)&3)  (swizzle via source address).
    const int r0 = tid >> 2;
    const int c0 = (((tid & 3) ^ ((r0 >> 1) & 3))) * 8;   // swizzled source col
    // unit t+256 -> row r0+64: ((r0+64)>>1)&3 == (r0>>1)&3, so same c0.
    const unsigned short* ga0 = A  + (size_t)(bm * BM + r0) * K + c0;
    const unsigned short* ga1 = ga0 + (size_t)64 * K;
    const unsigned short* gb0 = Bw + (size_t)(bn * BN + r0) * K + c0;
    const unsigned short* gb1 = gb0 + (size_t)64 * K;
    unsigned short* lA0 = As + tid * 8;
    unsigned short* lA1 = As + tid * 8 + 2048;
    unsigned short* lB0 = Bs + tid * 8;
    unsigned short* lB1 = Bs + tid * 8 + 2048;

    f32x4 acc[4][4];
    #pragma unroll
    for (int mi = 0; mi < 4; mi++)
        #pragma unroll
        for (int ni = 0; ni < 4; ni++)
            acc[mi][ni] = (f32x4)0.0f;

    const int lane = tid & 63, wv = tid >> 6;
    const int wm = (wv & 1) * 64;          // wave m-origin within block tile
    const int wn = (wv >> 1) * 64;         // wave n-origin
    const int l16 = lane & 15, l4 = lane >> 4;
    const bf16x8* Asv = (const bf16x8*)As;
    const bf16x8* Bsv = (const bf16x8*)Bs;
    // Swizzled read: unit = (row)*4 + (l4 ^ ((row>>1)&3)); row = wm+mi*16+l16.
    // wm, mi*16 are multiples of 16 -> (row>>1)&3 == (l16>>1)&3.
    const int swz = ((l16 >> 1) & 3);
    const int afo = (wm + l16) * 4 + (l4 ^ swz);   // + mi*64 per fragment
    const int bfo = (wn + l16) * 4 + (l4 ^ swz);   // + ni*64 per fragment

    // ---- prologue: stage tile 0 ----
    __builtin_amdgcn_global_load_lds(
        (const __attribute__((address_space(1))) unsigned int*)ga0,
        (__attribute__((address_space(3))) unsigned int*)lA0, 16, 0, 0);
    __builtin_amdgcn_global_load_lds(
        (const __attribute__((address_space(1))) unsigned int*)ga1,
        (__attribute__((address_space(3))) unsigned int*)lA1, 16, 0, 0);
    __builtin_amdgcn_global_load_lds(
        (const __attribute__((address_space(1))) unsigned int*)gb0,
        (__attribute__((address_space(3))) unsigned int*)lB0, 16, 0, 0);
    __builtin_amdgcn_global_load_lds(
        (const __attribute__((address_space(1))) unsigned int*)gb1,
        (__attribute__((address_space(3))) unsigned int*)lB1, 16, 0, 0);

    for (int t = 0; t < NT; ++t) {
        __syncthreads();                   // vmcnt(0): stage(t) landed in LDS

        bf16x8 af[4], bf[4];
        #pragma unroll
        for (int mi = 0; mi < 4; mi++) af[mi] = Asv[afo + mi * 64];
        #pragma unroll
        for (int ni = 0; ni < 4; ni++) bf[ni] = Bsv[bfo + ni * 64];

        __syncthreads();                   // all waves' ds_reads complete

        if (t + 1 < NT) {                  // issue stage(t+1); lands during MFMA
            const int kc = (t + 1) * BK;
            __builtin_amdgcn_global_load_lds(
                (const __attribute__((address_space(1))) unsigned int*)(ga0 + kc),
                (__attribute__((address_space(3))) unsigned int*)lA0, 16, 0, 0);
            __builtin_amdgcn_global_load_lds(
                (const __attribute__((address_space(1))) unsigned int*)(ga1 + kc),
                (__attribute__((address_space(3))) unsigned int*)lA1, 16, 0, 0);
            __builtin_amdgcn_global_load_lds(
                (const __attribute__((address_space(1))) unsigned int*)(gb0 + kc),
                (__attribute__((address_space(3))) unsigned int*)lB0, 16, 0, 0);
            __builtin_amdgcn_global_load_lds(
                (const __attribute__((address_space(1))) unsigned int*)(gb1 + kc),
                (__attribute__((address_space(3))) unsigned int*)lB1, 16, 0, 0);
        }

        // Swapped operands: acc = bf x af accumulates the C^T fragment:
        // lane holds C[m = l16][n = l4*4 + r]  (within the 16x16 sub-tile).
        #pragma unroll
        for (int mi = 0; mi < 4; mi++)
            #pragma unroll
            for (int ni = 0; ni < 4; ni++)
                acc[mi][ni] = __builtin_amdgcn_mfma_f32_16x16x32_bf16(
                    bf[ni], af[mi], acc[mi][ni], 0, 0, 0);
    }

    const float qs = qp[0];
    #pragma unroll
    for (int mi = 0; mi < 4; mi++) {
        const int row = bm * BM + wm + mi * 16 + l16;
        float* crow = C + (size_t)row * N;
        #pragma unroll
        for (int ni = 0; ni < 4; ni++) {
            const int colb = bn * BN + wn + ni * 16 + l4 * 4;
            f32x4 bv = *(const f32x4*)(bias + colb);
            f32x4 v  = acc[mi][ni];
            f32x4 out;
            out[0] = v[0] * qs + bv[0];
            out[1] = v[1] * qs + bv[1];
            out[2] = v[2] * qs + bv[2];
            out[3] = v[3] * qs + bv[3];
            *(f32x4*)(crow + colb) = out;
        }
    }
}

extern "C" void kernel_launch(void* const* d_in, const int* in_sizes, int n_in,
                              void* d_out, int out_size, void* d_ws, size_t ws_size,
                              hipStream_t stream) {
    const float* x      = (const float*)d_in[0];
    const float* qw     = (const float*)d_in[1];
    const float* rw     = (const float*)d_in[2];
    const float* lw     = (const float*)d_in[3];
    const float* bias   = (const float*)d_in[4];
    const float* scales = (const float*)d_in[5];

    char* ws = (char*)d_ws;
    // Workspace layout (all 16B aligned): total ~74.6 MiB
    unsigned short* xq = (unsigned short*)ws;                          // 75,497,472 B
    unsigned short* wc = (unsigned short*)(ws + 75497472);             //  2,654,208 B
    float* partials    = (float*)(ws + 75497472 + 2654208);            //     16,384 B
    float* qp          = (float*)(ws + 75497472 + 2654208 + 16384);    //         64 B
    float* rs          = (float*)(ws + 75497472 + 2654208 + 16384 + 64);        // 4608 B

    k_prep  <<<MM_BLOCKS + WP_BLOCKS, 256, 0, stream>>>(x, scales, qw, rw, lw,
                                                        wc, rs, partials);
    k_quantf<<<QBLOCKS, 256, 0, stream>>>(x, rs, partials, qp, xq);

    dim3 grid(M_DIM / BM, OUT_DIM / BN);   // 256 x 9
    k_gemm<<<grid, 256, 0, stream>>>(xq, wc, bias, qp, (float*)d_out);
}